// Round 1
// baseline (88.361 us; speedup 1.0000x reference)
//
#include <hip/hip_runtime.h>
#include <math.h>

// Soft silhouette renderer — R19 = R18 + LDS band-data compaction.
// verts: (4, 778, 3) f32   faces: (1538, 3) i32   out: (4, 320, 320) f32
//
// Verified-exact math core (R4, absmax 0.0):
//   area2 = fma(dx1, dy2, -round(dy1*dx2)) — matches the reference
//   evaluator's contraction; degenerate faces (sgn=0 -> 1/8 veil, i1==i2
//   sliver -> sigma=1/2 ridge) fall out of the generic edge code.
//
// R18 post-mortem: 82.4us total, but rocprof top-5 is ALL 256MiB ws-poison
// fills (~40us @ 6.7TB/s memset roofline) => silhouette_ws < 39.8us and
// dur_us ~= 40us fixed poison tax + ~2us prep + ~38us silhouette. Only
// silhouette is ours to optimize.
//
// R19 theory: the j-loop is a serial latency chain per 2 faces:
//   ds_read sIdx (~120cy) -> readfirstlane -> 6x uniform global float4
//   (L2 ~200cy) -> compute. Uniform loads = 48B per L2 round-trip, pure
//   latency. But at staging time the classifying thread ALREADY HOLDS
//   e0/e1/e2 in registers — so compact the 48B payload into LDS instead
//   of the index:
//  * staging writes sE0/sE1/sE2[pos] (rank-consecutive b128 writes,
//    conflict-free) — sIdx and the readfirstlane indirection are gone.
//  * j-loop reads 6x ds_read_b128 at wave-uniform addresses derived
//    from j (broadcast, conflict-free, ~12cy each) — no global traffic,
//    no inter-iteration dependency except acc.
//  * B4 barrier dropped: next chunk's sE writes happen after B2, which
//    every wave passes only after finishing the previous j-loop.
// LDS: 772*3*16B + 1KB = ~38.1KB -> 4 blocks/CU if LDS-bound (likely
// VGPR-bound near 16 waves/CU already; if staging regresses, shrink
// CHUNK_F to 512 next round).
// Keeps everything else from R18: 256-thr, 8x8 tiles, 2 chunks, alive-vote
// before staging, ballot-scan compaction, cover-count fold, per-lane live
// gate, 2x-unrolled branchless j-loop body, T_CUT=12, ACC_CUT=e^-13.
//
// Error budget vs 2e-2 tolerance (measured 0.00390625 = one bf16 ulp =
// harness quantization floor since R5): cull skip <= 1538*e^-12 = 9.4e-3
// worst-case; branchless factor ~1e-7/face; saturation cut 2.3e-6;
// product rounding ~1e-4. Compaction reorders nothing (same ballot-scan
// order as R18); payload bits identical to the gE arrays.

#define IMG_S 320
#define N_FACES 1538
#define N_VERTS 778
#define N_BATCH 4
#define FP 1600            // padded face stride in ws
#define TILE 8
#define CHUNK_F 768        // faces per chunk (2 chunks: 768 + 770)
#define MAXB 772           // LDS band capacity (>= max chunk size 770)
#define NWAVE 4
#define INV_SIGMA 100.0f
#define T_CUT 12.0f
#define ACC_CUT_P 2.2603294e-6f    // e^-13, product-domain saturation
#define LOG2_1EM6 -19.9315686f     // log2(1e-6)

__global__ __launch_bounds__(256)
void prep_faces(const float* __restrict__ verts,
                const int* __restrict__ faces,
                float4* __restrict__ gE0,
                float4* __restrict__ gE1,
                float4* __restrict__ gE2)
{
    const int f = blockIdx.x * 256 + threadIdx.x;
    const int b = blockIdx.z;
    if (f >= N_FACES) return;

    const float* vb = verts + (size_t)b * N_VERTS * 3;
    const int i0 = faces[f * 3 + 0];
    const int i1 = faces[f * 3 + 1];
    const int i2 = faces[f * 3 + 2];
    const float x0 = vb[i0 * 3 + 0], y0 = -vb[i0 * 3 + 1];
    const float x1 = vb[i1 * 3 + 0], y1 = -vb[i1 * 3 + 1];
    const float x2 = vb[i2 * 3 + 0], y2 = -vb[i2 * 3 + 1];

    // VERIFIED-EXACT (R4): fma-contracted area2 — do not change.
    const float dx1 = x1 - x0, dy1 = y1 - y0;
    const float dx2 = x2 - x0, dy2 = y2 - y0;
    const float area2 = __builtin_fmaf(dx1, dy2, -__fmul_rn(dy1, dx2));
    const float sgn = (area2 > 0.0f) ? 1.0f : ((area2 < 0.0f) ? -1.0f : 0.0f);

    const size_t o = (size_t)b * FP + f;
    {   // edge v0 -> v1
        const float ex = x1 - x0, ey = y1 - y0;
        const float s = sgn * INV_SIGMA / (sqrtf(ex * ex + ey * ey) + 1e-8f);
        gE0[o] = make_float4(-s * ey, s * ex, s * (ey * x0 - ex * y0), 0.0f);
    }
    {   // edge v1 -> v2
        const float ex = x2 - x1, ey = y2 - y1;
        const float s = sgn * INV_SIGMA / (sqrtf(ex * ex + ey * ey) + 1e-8f);
        gE1[o] = make_float4(-s * ey, s * ex, s * (ey * x1 - ex * y1), 0.0f);
    }
    {   // edge v2 -> v0
        const float ex = x0 - x2, ey = y0 - y2;
        const float s = sgn * INV_SIGMA / (sqrtf(ex * ex + ey * ey) + 1e-8f);
        gE2[o] = make_float4(-s * ey, s * ex, s * (ey * x2 - ex * y2), 0.0f);
    }
}

__global__ __launch_bounds__(256)
void silhouette_ws(const float4* __restrict__ gE0,
                   const float4* __restrict__ gE1,
                   const float4* __restrict__ gE2,
                   float* __restrict__ out)
{
    __shared__ float4 sE0[MAXB];   // compacted band-face edge payloads
    __shared__ float4 sE1[MAXB];
    __shared__ float4 sE2[MAXB];
    __shared__ float sAcc[256];
    __shared__ int sCount;
    __shared__ int sAlive;
    __shared__ int sCover;

    const int t    = threadIdx.x;
    const int wave = t >> 6;
    const int lane = t & 63;
    const int p    = t & 63;          // pixel id within 8x8 tile
    const int plx  = p & 7;
    const int ply  = p >> 3;
    const int b    = blockIdx.z;
    const int gx   = blockIdx.x * TILE + plx;
    const int gy   = blockIdx.y * TILE + ply;

    const float w  = 2.0f / IMG_S;
    const float px = (gx + 0.5f) * w - 1.0f;
    const float py = (gy + 0.5f) * w - 1.0f;
    const float cx = (blockIdx.x * TILE + 4) * w - 1.0f;
    const float cy = (blockIdx.y * TILE + 4) * w - 1.0f;
    const float rr = 3.5f * w;

    const float4* gb0 = gE0 + (size_t)b * FP;   // per-batch base
    const float4* gb1 = gE1 + (size_t)b * FP;
    const float4* gb2 = gE2 + (size_t)b * FP;

    float acc = 1.0f;   // product of (1-prob) over this wave's face subset
                        // (wave 0 also carries the cover factors)

    for (int c = 0; c < 2; ++c) {
        const int base = c * CHUNK_F;
        const int end  = (c == 0) ? CHUNK_F : N_FACES;

        sAcc[t] = acc;
        if (t == 0) { sCount = 0; sAlive = 0; sCover = 0; }
        __syncthreads();   // B1: resets + partials visible

        const float tot = sAcc[p] * sAcc[p + 64] * sAcc[p + 128] * sAcc[p + 192];
        const bool alive = (tot > ACC_CUT_P);
        if (alive) sAlive = 1;               // benign same-value race
        __syncthreads();   // B2: vote final — break BEFORE staging
                           // (also fences prev chunk's j-loop sE reads
                           //  from this chunk's sE writes below)

        if (sAlive == 0) break;   // uniform: every pixel saturated

        // ---- staging: classify faces, compact band PAYLOADS into LDS ----
        for (int fb = base; fb < end; fb += 256) {
            const int fc = fb + t;
            const bool vald = (fc < end);
            const int fcc = vald ? fc : (end - 1);
            const float4 e0 = gb0[fcc];      // coalesced vector loads
            const float4 e1 = gb1[fcc];
            const float4 e2 = gb2[fcc];
            const float c0 = fmaf(e0.x, cx, fmaf(e0.y, cy, e0.z));
            const float c1 = fmaf(e1.x, cx, fmaf(e1.y, cy, e1.z));
            const float c2 = fmaf(e2.x, cx, fmaf(e2.y, cy, e2.z));
            const float r0 = rr * (fabsf(e0.x) + fabsf(e0.y));
            const float r1 = rr * (fabsf(e1.x) + fabsf(e1.y));
            const float r2 = rr * (fabsf(e2.x) + fabsf(e2.y));
            const float m_hi = fminf(c0 + r0, fminf(c1 + r1, c2 + r2));
            const float m_lo = fminf(c0 - r0, fminf(c1 - r1, c2 - r2));
            const bool isCov  = vald && (m_lo > T_CUT);
            const bool isBand = vald && !isCov && (m_hi > -T_CUT);

            const unsigned long long mb = __ballot(isBand);
            int wbase = 0;
            if (lane == 0) {
                const int nw = __popcll(mb);
                if (nw) wbase = atomicAdd(&sCount, nw);
            }
            wbase = __shfl(wbase, 0);
            if (isBand) {
                const int pos = wbase + __popcll(mb & ((1ull << lane) - 1ull));
                sE0[pos] = e0;               // payload compaction: the data
                sE1[pos] = e1;               // is already in registers —
                sE2[pos] = e2;               // j-loop never touches global
            }
            const unsigned long long mc = __ballot(isCov);
            if (lane == 0) {
                const int ncv = __popcll(mc);
                if (ncv) atomicAdd(&sCover, ncv);
            }
        }
        __syncthreads();   // B3: compaction + cover count final

        const float coverF = exp2f((float)sCover * LOG2_1EM6);
        bool live = alive && (acc * coverF > ACC_CUT_P);
        if (wave == 0) acc *= coverF;

        const int n = sCount;
        int j = wave;
        while (j < n) {
            if (__ballot(live) == 0ull) break;   // whole wave saturated
            const int j1 = j + NWAVE;
            const int j1c = (j1 < n) ? j1 : j;
            // issue both iterations' LDS broadcasts before any compute
            const float4 A0 = sE0[j],   A1 = sE1[j],   A2 = sE2[j];
            const float4 B0 = sE0[j1c], B1 = sE1[j1c], B2 = sE2[j1c];
            {   // iteration 0 — branchless band body
                const float xa = fmaf(A0.x, px, fmaf(A0.y, py, A0.z));
                const float xb = fmaf(A1.x, px, fmaf(A1.y, py, A1.z));
                const float xc = fmaf(A2.x, px, fmaf(A2.y, py, A2.z));
                const float m = fminf(xa, fminf(xb, xc));
                if (live && m > -T_CUT) {
                    const float da = 1.0f + __expf(-xa);
                    const float db = 1.0f + __expf(-xb);
                    const float dc = 1.0f + __expf(-xc);
                    const float f = fmaxf(
                        1.0f - __builtin_amdgcn_rcpf(da * db * dc), 1e-6f);
                    acc *= f;
                    live = (acc > ACC_CUT_P);
                }
            }
            if (j1 < n) {   // iteration 1
                const float xa = fmaf(B0.x, px, fmaf(B0.y, py, B0.z));
                const float xb = fmaf(B1.x, px, fmaf(B1.y, py, B1.z));
                const float xc = fmaf(B2.x, px, fmaf(B2.y, py, B2.z));
                const float m = fminf(xa, fminf(xb, xc));
                if (live && m > -T_CUT) {
                    const float da = 1.0f + __expf(-xa);
                    const float db = 1.0f + __expf(-xb);
                    const float dc = 1.0f + __expf(-xc);
                    const float f = fmaxf(
                        1.0f - __builtin_amdgcn_rcpf(da * db * dc), 1e-6f);
                    acc *= f;
                    live = (acc > ACC_CUT_P);
                }
            }
            j += 2 * NWAVE;
        }
        // no B4: next chunk's sE writes happen after its B2, which every
        // wave passes only after finishing this j-loop.
    }

    // final reduction + output (loop exits are block-uniform)
    sAcc[t] = acc;
    __syncthreads();
    if (t < 64) {
        const float tot = sAcc[p] * sAcc[p + 64] * sAcc[p + 128] * sAcc[p + 192];
        out[(size_t)b * (IMG_S * IMG_S) + (size_t)gy * IMG_S + gx] = 1.0f - tot;
    }
}

extern "C" void kernel_launch(void* const* d_in, const int* in_sizes, int n_in,
                              void* d_out, int out_size, void* d_ws, size_t ws_size,
                              hipStream_t stream) {
    const float* verts = (const float*)d_in[0];
    const int* faces = (const int*)d_in[1];
    float* out = (float*)d_out;

    // ws layout: 3 arrays of float4[N_BATCH * FP]  (3 * 4*1600*16B = 307 KB)
    float4* gE0 = (float4*)d_ws;
    float4* gE1 = gE0 + (size_t)N_BATCH * FP;
    float4* gE2 = gE1 + (size_t)N_BATCH * FP;

    dim3 pgrid((N_FACES + 255) / 256, 1, N_BATCH);
    prep_faces<<<pgrid, 256, 0, stream>>>(verts, faces, gE0, gE1, gE2);

    dim3 grid(IMG_S / TILE, IMG_S / TILE, N_BATCH);
    silhouette_ws<<<grid, 256, 0, stream>>>(gE0, gE1, gE2, out);
}

// Round 2
// 81.735 us; speedup vs baseline: 1.0811x; 1.0811x over previous
//
#include <hip/hip_runtime.h>
#include <math.h>

// Soft silhouette renderer — R20 = R19 (LDS payload compaction) with the
// occupancy regression fixed: CHUNK_F 768 -> 384 (4 chunks), LDS 38.1KB
// -> 19.7KB, restoring ~8 blocks/CU.
// verts: (4, 778, 3) f32   faces: (1538, 3) i32   out: (4, 320, 320) f32
//
// Verified-exact math core (R4, absmax 0.0):
//   area2 = fma(dx1, dy2, -round(dy1*dx2)) — matches the reference
//   evaluator's contraction; degenerate faces (sgn=0 -> 1/8 veil, i1==i2
//   sliver -> sigma=1/2 ridge) fall out of the generic edge code.
//
// R19 post-mortem: payload-compaction REGRESSED 82.4 -> 88.4us. The LDS
// band buffer (772 faces * 48B = 38.1KB) capped the kernel at 4 blocks/CU
// (16 waves) vs R18's ~8 blocks (32 waves). Both phases are latency-bound
// and live on TLP: staging's coalesced global loads and the j-loop's
// ~120cy LDS reads each need 6-8 waves/SIMD of cover. The occupancy
// halving cost more than the removed s_load chain saved (Guideline-1
// failure, same shape as the m132 BK=128 LDS/occupancy trade).
//
// R20: keep the payload compaction (j-loop stays pure LDS broadcast —
// no index indirection, no uniform global loads), but size the band
// buffer to ONE 384-face chunk: 3 * 388 * 16B + 1KB = 19.7KB -> 8
// blocks/CU LDS-wise. Staging work is identical (every face classified
// once per sweep; 8 vs 7 passes of 256); 2 extra barrier triplets are
// sub-us; finer chunks also sharpen the saturation early-exit.
// Keeps everything else: 256-thr, 8x8 tiles, alive-vote before staging,
// ballot-scan compaction, cover-count fold, per-lane live gate,
// 2x-unrolled branchless j-loop body, T_CUT=12, ACC_CUT=e^-13.
//
// Error budget vs 2e-2 tolerance (measured 0.00390625 = one bf16 ulp =
// harness quantization floor since R5): cull skip <= 1538*e^-12 = 9.4e-3
// worst-case; branchless factor ~1e-7/face; saturation cut 2.3e-6;
// product rounding ~1e-4. Chunk split changes only the grouping of the
// per-wave products, not their values (fp product order within a wave's
// subset is preserved face-by-face).

#define IMG_S 320
#define N_FACES 1538
#define N_VERTS 778
#define N_BATCH 4
#define FP 1600            // padded face stride in ws
#define TILE 8
#define CHUNK_F 384        // faces per chunk (4 chunks: 384,384,384,386)
#define N_CHUNKS 4
#define MAXB 388           // LDS band capacity (>= max chunk size 386)
#define NWAVE 4
#define INV_SIGMA 100.0f
#define T_CUT 12.0f
#define ACC_CUT_P 2.2603294e-6f    // e^-13, product-domain saturation
#define LOG2_1EM6 -19.9315686f     // log2(1e-6)

__global__ __launch_bounds__(256)
void prep_faces(const float* __restrict__ verts,
                const int* __restrict__ faces,
                float4* __restrict__ gE0,
                float4* __restrict__ gE1,
                float4* __restrict__ gE2)
{
    const int f = blockIdx.x * 256 + threadIdx.x;
    const int b = blockIdx.z;
    if (f >= N_FACES) return;

    const float* vb = verts + (size_t)b * N_VERTS * 3;
    const int i0 = faces[f * 3 + 0];
    const int i1 = faces[f * 3 + 1];
    const int i2 = faces[f * 3 + 2];
    const float x0 = vb[i0 * 3 + 0], y0 = -vb[i0 * 3 + 1];
    const float x1 = vb[i1 * 3 + 0], y1 = -vb[i1 * 3 + 1];
    const float x2 = vb[i2 * 3 + 0], y2 = -vb[i2 * 3 + 1];

    // VERIFIED-EXACT (R4): fma-contracted area2 — do not change.
    const float dx1 = x1 - x0, dy1 = y1 - y0;
    const float dx2 = x2 - x0, dy2 = y2 - y0;
    const float area2 = __builtin_fmaf(dx1, dy2, -__fmul_rn(dy1, dx2));
    const float sgn = (area2 > 0.0f) ? 1.0f : ((area2 < 0.0f) ? -1.0f : 0.0f);

    const size_t o = (size_t)b * FP + f;
    {   // edge v0 -> v1
        const float ex = x1 - x0, ey = y1 - y0;
        const float s = sgn * INV_SIGMA / (sqrtf(ex * ex + ey * ey) + 1e-8f);
        gE0[o] = make_float4(-s * ey, s * ex, s * (ey * x0 - ex * y0), 0.0f);
    }
    {   // edge v1 -> v2
        const float ex = x2 - x1, ey = y2 - y1;
        const float s = sgn * INV_SIGMA / (sqrtf(ex * ex + ey * ey) + 1e-8f);
        gE1[o] = make_float4(-s * ey, s * ex, s * (ey * x1 - ex * y1), 0.0f);
    }
    {   // edge v2 -> v0
        const float ex = x0 - x2, ey = y0 - y2;
        const float s = sgn * INV_SIGMA / (sqrtf(ex * ex + ey * ey) + 1e-8f);
        gE2[o] = make_float4(-s * ey, s * ex, s * (ey * x2 - ex * y2), 0.0f);
    }
}

__global__ __launch_bounds__(256)
void silhouette_ws(const float4* __restrict__ gE0,
                   const float4* __restrict__ gE1,
                   const float4* __restrict__ gE2,
                   float* __restrict__ out)
{
    __shared__ float4 sE0[MAXB];   // compacted band-face edge payloads
    __shared__ float4 sE1[MAXB];
    __shared__ float4 sE2[MAXB];
    __shared__ float sAcc[256];
    __shared__ int sCount;
    __shared__ int sAlive;
    __shared__ int sCover;

    const int t    = threadIdx.x;
    const int wave = t >> 6;
    const int lane = t & 63;
    const int p    = t & 63;          // pixel id within 8x8 tile
    const int plx  = p & 7;
    const int ply  = p >> 3;
    const int b    = blockIdx.z;
    const int gx   = blockIdx.x * TILE + plx;
    const int gy   = blockIdx.y * TILE + ply;

    const float w  = 2.0f / IMG_S;
    const float px = (gx + 0.5f) * w - 1.0f;
    const float py = (gy + 0.5f) * w - 1.0f;
    const float cx = (blockIdx.x * TILE + 4) * w - 1.0f;
    const float cy = (blockIdx.y * TILE + 4) * w - 1.0f;
    const float rr = 3.5f * w;

    const float4* gb0 = gE0 + (size_t)b * FP;   // per-batch base
    const float4* gb1 = gE1 + (size_t)b * FP;
    const float4* gb2 = gE2 + (size_t)b * FP;

    float acc = 1.0f;   // product of (1-prob) over this wave's face subset
                        // (wave 0 also carries the cover factors)

    for (int c = 0; c < N_CHUNKS; ++c) {
        const int base = c * CHUNK_F;
        const int end  = (c == N_CHUNKS - 1) ? N_FACES : base + CHUNK_F;

        sAcc[t] = acc;
        if (t == 0) { sCount = 0; sAlive = 0; sCover = 0; }
        __syncthreads();   // B1: resets + partials visible

        const float tot = sAcc[p] * sAcc[p + 64] * sAcc[p + 128] * sAcc[p + 192];
        const bool alive = (tot > ACC_CUT_P);
        if (alive) sAlive = 1;               // benign same-value race
        __syncthreads();   // B2: vote final — break BEFORE staging
                           // (also fences prev chunk's j-loop sE reads
                           //  from this chunk's sE writes below)

        if (sAlive == 0) break;   // uniform: every pixel saturated

        // ---- staging: classify faces, compact band PAYLOADS into LDS ----
        for (int fb = base; fb < end; fb += 256) {
            const int fc = fb + t;
            const bool vald = (fc < end);
            const int fcc = vald ? fc : (end - 1);
            const float4 e0 = gb0[fcc];      // coalesced vector loads
            const float4 e1 = gb1[fcc];
            const float4 e2 = gb2[fcc];
            const float c0 = fmaf(e0.x, cx, fmaf(e0.y, cy, e0.z));
            const float c1 = fmaf(e1.x, cx, fmaf(e1.y, cy, e1.z));
            const float c2 = fmaf(e2.x, cx, fmaf(e2.y, cy, e2.z));
            const float r0 = rr * (fabsf(e0.x) + fabsf(e0.y));
            const float r1 = rr * (fabsf(e1.x) + fabsf(e1.y));
            const float r2 = rr * (fabsf(e2.x) + fabsf(e2.y));
            const float m_hi = fminf(c0 + r0, fminf(c1 + r1, c2 + r2));
            const float m_lo = fminf(c0 - r0, fminf(c1 - r1, c2 - r2));
            const bool isCov  = vald && (m_lo > T_CUT);
            const bool isBand = vald && !isCov && (m_hi > -T_CUT);

            const unsigned long long mb = __ballot(isBand);
            int wbase = 0;
            if (lane == 0) {
                const int nw = __popcll(mb);
                if (nw) wbase = atomicAdd(&sCount, nw);
            }
            wbase = __shfl(wbase, 0);
            if (isBand) {
                const int pos = wbase + __popcll(mb & ((1ull << lane) - 1ull));
                sE0[pos] = e0;               // payload compaction: the data
                sE1[pos] = e1;               // is already in registers —
                sE2[pos] = e2;               // j-loop never touches global
            }
            const unsigned long long mc = __ballot(isCov);
            if (lane == 0) {
                const int ncv = __popcll(mc);
                if (ncv) atomicAdd(&sCover, ncv);
            }
        }
        __syncthreads();   // B3: compaction + cover count final

        const float coverF = exp2f((float)sCover * LOG2_1EM6);
        bool live = alive && (acc * coverF > ACC_CUT_P);
        if (wave == 0) acc *= coverF;

        const int n = sCount;
        int j = wave;
        while (j < n) {
            if (__ballot(live) == 0ull) break;   // whole wave saturated
            const int j1 = j + NWAVE;
            const int j1c = (j1 < n) ? j1 : j;
            // issue both iterations' LDS broadcasts before any compute
            const float4 A0 = sE0[j],   A1 = sE1[j],   A2 = sE2[j];
            const float4 B0 = sE0[j1c], B1 = sE1[j1c], B2 = sE2[j1c];
            {   // iteration 0 — branchless band body
                const float xa = fmaf(A0.x, px, fmaf(A0.y, py, A0.z));
                const float xb = fmaf(A1.x, px, fmaf(A1.y, py, A1.z));
                const float xc = fmaf(A2.x, px, fmaf(A2.y, py, A2.z));
                const float m = fminf(xa, fminf(xb, xc));
                if (live && m > -T_CUT) {
                    const float da = 1.0f + __expf(-xa);
                    const float db = 1.0f + __expf(-xb);
                    const float dc = 1.0f + __expf(-xc);
                    const float f = fmaxf(
                        1.0f - __builtin_amdgcn_rcpf(da * db * dc), 1e-6f);
                    acc *= f;
                    live = (acc > ACC_CUT_P);
                }
            }
            if (j1 < n) {   // iteration 1
                const float xa = fmaf(B0.x, px, fmaf(B0.y, py, B0.z));
                const float xb = fmaf(B1.x, px, fmaf(B1.y, py, B1.z));
                const float xc = fmaf(B2.x, px, fmaf(B2.y, py, B2.z));
                const float m = fminf(xa, fminf(xb, xc));
                if (live && m > -T_CUT) {
                    const float da = 1.0f + __expf(-xa);
                    const float db = 1.0f + __expf(-xb);
                    const float dc = 1.0f + __expf(-xc);
                    const float f = fmaxf(
                        1.0f - __builtin_amdgcn_rcpf(da * db * dc), 1e-6f);
                    acc *= f;
                    live = (acc > ACC_CUT_P);
                }
            }
            j += 2 * NWAVE;
        }
        // no B4: next chunk's sE writes happen after its B2, which every
        // wave passes only after finishing this j-loop.
    }

    // final reduction + output (loop exits are block-uniform)
    sAcc[t] = acc;
    __syncthreads();
    if (t < 64) {
        const float tot = sAcc[p] * sAcc[p + 64] * sAcc[p + 128] * sAcc[p + 192];
        out[(size_t)b * (IMG_S * IMG_S) + (size_t)gy * IMG_S + gx] = 1.0f - tot;
    }
}

extern "C" void kernel_launch(void* const* d_in, const int* in_sizes, int n_in,
                              void* d_out, int out_size, void* d_ws, size_t ws_size,
                              hipStream_t stream) {
    const float* verts = (const float*)d_in[0];
    const int* faces = (const int*)d_in[1];
    float* out = (float*)d_out;

    // ws layout: 3 arrays of float4[N_BATCH * FP]  (3 * 4*1600*16B = 307 KB)
    float4* gE0 = (float4*)d_ws;
    float4* gE1 = gE0 + (size_t)N_BATCH * FP;
    float4* gE2 = gE1 + (size_t)N_BATCH * FP;

    dim3 pgrid((N_FACES + 255) / 256, 1, N_BATCH);
    prep_faces<<<pgrid, 256, 0, stream>>>(verts, faces, gE0, gE1, gE2);

    dim3 grid(IMG_S / TILE, IMG_S / TILE, N_BATCH);
    silhouette_ws<<<grid, 256, 0, stream>>>(gE0, gE1, gE2, out);
}